// Round 4
// baseline (704.357 us; speedup 1.0000x reference)
//
#include <hip/hip_runtime.h>

// Problem constants
#define BB 32
#define CC 128
#define HW 1024            // 32*32
#define NN 32768           // BB*HW
#define KK 1024            // num embeddings
#define DD 128             // embedding dim
// Output offsets (floats): (loss, quantized_nchw, perplexity, encodings, top_k_quantized)
#define OFF_QUANT 1
#define OFF_PERP  4194305
#define OFF_ENC   4194306
#define OFF_TOPK  37748738

// ws layout (bytes)
#define WS_PARTIALS 0          // 512 doubles used
#define WS_HIST     32768      // 1024 ints
#define WS_CAND8    36864      // 32768*8 ints = 1 MiB
#define WS_TOP3     1085440    // 32768*4 ints = 512 KiB
#define WS_EMBBF    1609728    // 1024*128 ushort = 256 KiB
#define WS_ENORM    1871872    // 1024 float = 4 KiB

typedef __attribute__((ext_vector_type(8))) short short8;
typedef __attribute__((ext_vector_type(4))) float f32x4;
typedef __attribute__((ext_vector_type(2))) float f32x2;

__device__ __forceinline__ ushort f32_to_bf16(float v) {
    uint u = __float_as_uint(v);
    u = (u + 0x7FFFu + ((u >> 16) & 1u)) >> 16;   // RNE
    return (ushort)u;
}

// ---------------------------------------------------------------------------
// kP: prep. Blocks 0..127: x fp32 NCHW -> xbf bf16 [N][128].
//            Blocks 128..143: emb fp32 -> bf16 + fp32 row norms.
//            Block 128 also zeroes the histogram.
// ---------------------------------------------------------------------------
__global__ __launch_bounds__(256) void kP_prep(
    const float* __restrict__ in, const float* __restrict__ emb,
    ushort* __restrict__ xbf, ushort* __restrict__ embbf,
    float* __restrict__ enorm, int* __restrict__ hist)
{
    const int blk = blockIdx.x, t = threadIdx.x;
    if (blk < 128) {
        const int n  = blk * 256 + t;
        const int b  = n >> 10, hw = n & 1023;
        const float* src = in + (size_t)b * (CC * HW) + hw;
        short8* dst = (short8*)(xbf + (size_t)n * 128);
#pragma unroll 2
        for (int c0 = 0; c0 < 16; ++c0) {
            union { short8 v; ushort u[8]; } p;
#pragma unroll
            for (int j = 0; j < 8; ++j)
                p.u[j] = f32_to_bf16(src[(size_t)(c0 * 8 + j) * HW]);
            dst[c0] = p.v;
        }
    } else {
        const int rr = t >> 2, q = t & 3;
        const int row = (blk - 128) * 64 + rr;
        const float4* src = (const float4*)(emb + (size_t)row * 128 + q * 32);
        short8* dst = (short8*)(embbf + (size_t)row * 128 + q * 32);
        float nrm = 0.f;
#pragma unroll
        for (int u2 = 0; u2 < 4; ++u2) {
            float4 a = src[u2 * 2], b = src[u2 * 2 + 1];
            float f[8] = {a.x, a.y, a.z, a.w, b.x, b.y, b.z, b.w};
            union { short8 v; ushort u[8]; } p;
#pragma unroll
            for (int j = 0; j < 8; ++j) {
                nrm = fmaf(f[j], f[j], nrm);
                p.u[j] = f32_to_bf16(f[j]);
            }
            dst[u2] = p.v;
        }
        nrm += __shfl_xor(nrm, 1);
        nrm += __shfl_xor(nrm, 2);
        if (q == 0) enorm[row] = nrm;
        if (blk == 128)
            for (int i = t; i < 1024; i += 256) hist[i] = 0;
    }
}

// ---------------------------------------------------------------------------
// kA2: bf16-MFMA candidate pass.
// ---------------------------------------------------------------------------
__global__ __launch_bounds__(128) void kA2_candidates(
    const ushort* __restrict__ xbf, const ushort* __restrict__ embbf,
    const float* __restrict__ enorm, int* __restrict__ cand8)
{
    __shared__ uint4 et16[2048];      // 32KB emb tile, aliased as merge buffer
    __shared__ float enl[1024];       // 4KB emb norms
    uint* keybuf = (uint*)et16;

    const int t    = threadIdx.x;
    const int lane = t & 63, w = t >> 6;
    const int quad = lane >> 4, m = lane & 15;
    const int rowBase = blockIdx.x * 64;
    const int rw = rowBase + w * 32;

    for (int i = t; i < 1024; i += 128) enl[i] = enorm[i];

    short8 A[2][4];
#pragma unroll
    for (int s = 0; s < 2; ++s)
#pragma unroll
    for (int kk = 0; kk < 4; ++kk)
        A[s][kk] = *(const short8*)(xbf + (size_t)(rw + s * 16 + m) * 128 + kk * 32 + quad * 8);

    uint kq[2][4][3];
#pragma unroll
    for (int s = 0; s < 2; ++s)
#pragma unroll
    for (int i = 0; i < 4; ++i)
        kq[s][i][0] = kq[s][i][1] = kq[s][i][2] = 0xFFFFFFFFu;

    const uint4* eg = (const uint4*)embbf;

    for (int tile = 0; tile < 8; ++tile) {
        __syncthreads();
#pragma unroll
        for (int u = 0; u < 16; ++u) {
            int c = u * 128 + t;
            int row = c >> 4, kb = c & 15;
            et16[row * 16 + (kb ^ (row & 7))] = eg[(size_t)(tile * 128 + row) * 16 + kb];
        }
        __syncthreads();
#pragma unroll
        for (int sub = 0; sub < 8; ++sub) {
            f32x4 acc0 = {0.f, 0.f, 0.f, 0.f}, acc1 = {0.f, 0.f, 0.f, 0.f};
#pragma unroll
            for (int kk = 0; kk < 4; ++kk) {
                short8 B = *(const short8*)&et16[(sub * 16 + m) * 16 + ((kk * 4 + quad) ^ (m & 7))];
                acc0 = __builtin_amdgcn_mfma_f32_16x16x32_bf16(A[0][kk], B, acc0, 0, 0, 0);
                acc1 = __builtin_amdgcn_mfma_f32_16x16x32_bf16(A[1][kk], B, acc1, 0, 0, 0);
            }
            const int col = tile * 128 + sub * 16 + m;
            const float en = enl[col];
#pragma unroll
            for (int i = 0; i < 4; ++i) {
                {
                    float sc = fmaf(-2.f, acc0[i], en);
                    uint u = __float_as_uint(sc);
                    u ^= (uint)(((int)u) >> 31) | 0x80000000u;   // sortable
                    uint key = (u & 0xFFFFFC00u) | (uint)col;
                    uint t0 = max(kq[0][i][0], key); kq[0][i][0] = min(kq[0][i][0], key);
                    uint t1 = max(kq[0][i][1], t0);  kq[0][i][1] = min(kq[0][i][1], t0);
                    kq[0][i][2] = min(kq[0][i][2], t1);
                }
                {
                    float sc = fmaf(-2.f, acc1[i], en);
                    uint u = __float_as_uint(sc);
                    u ^= (uint)(((int)u) >> 31) | 0x80000000u;
                    uint key = (u & 0xFFFFFC00u) | (uint)col;
                    uint t0 = max(kq[1][i][0], key); kq[1][i][0] = min(kq[1][i][0], key);
                    uint t1 = max(kq[1][i][1], t0);  kq[1][i][1] = min(kq[1][i][1], t0);
                    kq[1][i][2] = min(kq[1][i][2], t1);
                }
            }
        }
    }

    __syncthreads();
#pragma unroll
    for (int s = 0; s < 2; ++s)
#pragma unroll
    for (int i = 0; i < 4; ++i) {
        int rowl = w * 32 + s * 16 + quad * 4 + i;
#pragma unroll
        for (int j = 0; j < 3; ++j)
            keybuf[(m * 3 + j) * 65 + rowl] = kq[s][i][j];
    }
    __syncthreads();

    if (t < 64) {
        uint D[8];
#pragma unroll
        for (int s = 0; s < 8; ++s) D[s] = 0xFFFFFFFFu;
        for (int s = 0; s < 48; ++s) {
            uint k = keybuf[s * 65 + t];
            if (k < D[7]) {
                D[7] = k;
#pragma unroll
                for (int u = 7; u > 0; --u)
                    if (D[u] < D[u - 1]) { uint tmp = D[u]; D[u] = D[u - 1]; D[u - 1] = tmp; }
            }
        }
        int n = rowBase + t;
#pragma unroll
        for (int s = 0; s < 8; ++s) cand8[n * 8 + s] = (int)(D[s] & 1023u);
    }
}

// ---------------------------------------------------------------------------
// kB2: fp64 exact refine of 8 candidates -> true top-3 (tie-break by lower
// index). Also: 3rd-idx histogram + per-block fp64 loss partial (top-1 dist
// is exactly the e_latent_loss numerator).
// ---------------------------------------------------------------------------
__global__ __launch_bounds__(256) void kB2_refine(
    const float* __restrict__ in, const float* __restrict__ emb,
    const int* __restrict__ cand8, int* __restrict__ top3,
    int* __restrict__ hist, double* __restrict__ partials)
{
    __shared__ float x_lds[8192];   // [128][64]
    __shared__ double lsum[64];
    const int t = threadIdx.x;
    const int rowBase = blockIdx.x * 64;
    const int b = rowBase >> 10, hw0 = rowBase & 1023;
    const float* inB = in + (size_t)b * (CC * HW) + hw0;
    for (int i = t; i < 8192; i += 256) {
        int c = i >> 6, r = i & 63;
        x_lds[c * 64 + r] = inB[c * HW + r];
    }
    __syncthreads();

    const int r = t >> 2;     // row 0..63
    const int q = t & 3;      // c-chunk of 32
    const int n = rowBase + r;

    double dist[8]; int es[8];
    for (int s = 0; s < 8; ++s) {
        int e = cand8[n * 8 + s];
        es[s] = e;
        const float4* er = (const float4*)(emb + (size_t)e * DD + q * 32);
        double acc = 0.0;
#pragma unroll
        for (int u = 0; u < 8; ++u) {
            float4 ev = er[u];
            int c0 = q * 32 + u * 4;
            double a0 = (double)x_lds[(c0 + 0) * 64 + r] - (double)ev.x;
            double a1 = (double)x_lds[(c0 + 1) * 64 + r] - (double)ev.y;
            double a2 = (double)x_lds[(c0 + 2) * 64 + r] - (double)ev.z;
            double a3 = (double)x_lds[(c0 + 3) * 64 + r] - (double)ev.w;
            acc += a0 * a0 + a1 * a1 + a2 * a2 + a3 * a3;
        }
        acc += __shfl_xor(acc, 1);
        acc += __shfl_xor(acc, 2);
        dist[s] = acc;
    }

    if (q == 0) {
        bool used[8] = {false, false, false, false, false, false, false, false};
        int out_idx[3];
        double d_top1 = 0.0;
#pragma unroll
        for (int p = 0; p < 3; ++p) {
            double bd = 1.0e300; int bi = 0x7fffffff, bs = 0;
            for (int s = 0; s < 8; ++s) {
                if (used[s]) continue;
                if (dist[s] < bd || (dist[s] == bd && es[s] < bi)) {
                    bd = dist[s]; bi = es[s]; bs = s;
                }
            }
            used[bs] = true; out_idx[p] = bi;
            if (p == 0) d_top1 = bd;
        }
        top3[n * 4 + 0] = out_idx[0];
        top3[n * 4 + 1] = out_idx[1];
        top3[n * 4 + 2] = out_idx[2];
        atomicAdd(&hist[out_idx[2]], 1);
        lsum[r] = d_top1;
    }
    __syncthreads();
    if (t < 8) {
        double a = 0.0;
#pragma unroll
        for (int i = 0; i < 8; ++i) a += lsum[t * 8 + i];
        lsum[t] = a;
    }
    __syncthreads();
    if (t == 0) {
        double a = 0.0;
#pragma unroll
        for (int i = 0; i < 8; ++i) a += lsum[i];
        partials[blockIdx.x] = a;
    }
}

// ---------------------------------------------------------------------------
// kEpi: fused epilogue — one pass over all 201 MB of big outputs.
//   blocks 0..1023    : quantized_nchw (scalar stores; region is 4B-aligned)
//   blocks 1024..4095 : top_k_quantized (f32x2; region 8B-aligned)
//   blocks 4096..8191 : encodings zeros + inline one-hot (f32x2)
// All stores nontemporal (pure streaming writes).
// ---------------------------------------------------------------------------
__global__ __launch_bounds__(256) void kEpi(
    const float* __restrict__ emb, const int* __restrict__ top3,
    float* __restrict__ out)
{
    const int blk = blockIdx.x, t = threadIdx.x;
    if (blk < 1024) {
        // quantized: 4.19M floats, 16 per thread
        float* dst = out + OFF_QUANT;
#pragma unroll 4
        for (int u = 0; u < 16; ++u) {
            int j  = blk * 4096 + u * 256 + t;
            int hw = j & 1023;
            int c  = (j >> 10) & 127;
            int bb = j >> 17;
            int n  = bb * 1024 + hw;
            int e  = top3[n * 4];
            __builtin_nontemporal_store(emb[e * DD + c], dst + j);
        }
    } else if (blk < 4096) {
        // top_k_quantized: 6.29M f32x2, 8 per thread
        const f32x2* e2 = (const f32x2*)emb;
        f32x2* dst = (f32x2*)(out + OFF_TOPK);
#pragma unroll 4
        for (int u = 0; u < 8; ++u) {
            int j  = (blk - 1024) * 2048 + u * 256 + t;
            int c2 = j & 63;
            int n  = (j >> 6) & 32767;
            int k  = j >> 21;
            int e  = top3[n * 4 + k];
            __builtin_nontemporal_store(e2[e * 64 + c2], dst + j);
        }
    } else {
        // encodings: 8 rows/block, 512 f32x2/row, one-hot of top3[.+2]
        const int row0 = (blk - 4096) * 8;
        const int r8 = t >> 5, seg = t & 31;
        const int row = row0 + r8;
        const int e = top3[row * 4 + 2];
        f32x2* dst = (f32x2*)(out + OFF_ENC) + (size_t)row * 512 + seg * 16;
#pragma unroll
        for (int u = 0; u < 16; ++u) {
            f32x2 v = {0.f, 0.f};
            if (seg == (e >> 5) && u == ((e >> 1) & 15))
                v[e & 1] = 1.0f;
            __builtin_nontemporal_store(v, dst + u);
        }
    }
}

// ---------------------------------------------------------------------------
// kF: finalize loss (512 partials) + perplexity (fp64 reductions).
// ---------------------------------------------------------------------------
__global__ __launch_bounds__(1024) void kF_final(
    const double* __restrict__ partials, const int* __restrict__ hist,
    float* __restrict__ out)
{
    __shared__ double sred[1024];
    const int t = threadIdx.x;
    sred[t] = (t < 512) ? partials[t] : 0.0;
    __syncthreads();
    for (int s = 512; s > 0; s >>= 1) {
        if (t < s) sred[t] += sred[t + s];
        __syncthreads();
    }
    if (t == 0) out[0] = (float)(0.25 * sred[0] / 4194304.0);
    __syncthreads();
    double p = (double)hist[t] / 32768.0;
    sred[t] = p * log(p + 1e-10);
    __syncthreads();
    for (int s = 512; s > 0; s >>= 1) {
        if (t < s) sred[t] += sred[t + s];
        __syncthreads();
    }
    if (t == 0) out[OFF_PERP] = (float)exp(-sred[0]);
}

extern "C" void kernel_launch(void* const* d_in, const int* in_sizes, int n_in,
                              void* d_out, int out_size, void* d_ws, size_t ws_size,
                              hipStream_t stream)
{
    const float* in  = (const float*)d_in[0];
    const float* emb = (const float*)d_in[1];
    float* out = (float*)d_out;
    char*  ws  = (char*)d_ws;

    double* partials = (double*)(ws + WS_PARTIALS);
    int*    hist     = (int*)(ws + WS_HIST);
    int*    cand8    = (int*)(ws + WS_CAND8);
    int*    top3     = (int*)(ws + WS_TOP3);
    ushort* embbf    = (ushort*)(ws + WS_EMBBF);
    float*  enorm    = (float*)(ws + WS_ENORM);
    // xbf scratch lives in the top_k output region (16B-aligned at +2 floats);
    // kEpi's topk writes fully overwrite it afterwards.
    ushort* xbf = (ushort*)(out + OFF_TOPK + 2);

    kP_prep       <<<dim3(144), dim3(256), 0, stream>>>(in, emb, xbf, embbf, enorm, hist);
    kA2_candidates<<<dim3(512), dim3(128), 0, stream>>>(xbf, embbf, enorm, cand8);
    kB2_refine    <<<dim3(512), dim3(256), 0, stream>>>(in, emb, cand8, top3, hist, partials);
    kEpi          <<<dim3(8192), dim3(256), 0, stream>>>(emb, top3, out);
    kF_final      <<<dim3(1), dim3(1024), 0, stream>>>(partials, hist, out);
}

// Round 5
// 357.109 us; speedup vs baseline: 1.9724x; 1.9724x over previous
//
#include <hip/hip_runtime.h>

// Problem constants
#define BB 32
#define CC 128
#define HW 1024            // 32*32
#define NN 32768           // BB*HW
#define KK 1024            // num embeddings
#define DD 128             // embedding dim
// Output offsets (floats): (loss, quantized_nchw, perplexity, encodings, top_k_quantized)
#define OFF_QUANT 1
#define OFF_PERP  4194305
#define OFF_ENC   4194306
#define OFF_TOPK  37748738

// ws layout (bytes)
#define WS_PARTIALS 0          // 512 doubles used
#define WS_HIST     32768      // 1024 ints
#define WS_CAND8    36864      // 32768*8 ints = 1 MiB
#define WS_TOP3     1085440    // 32768*4 ints = 512 KiB
#define WS_EMBBF    1609728    // 1024*128 ushort = 256 KiB
#define WS_ENORM    1871872    // 1024 float = 4 KiB

typedef __attribute__((ext_vector_type(8))) short short8;
typedef __attribute__((ext_vector_type(4))) float f32x4;
typedef __attribute__((ext_vector_type(2))) float f32x2;

__device__ __forceinline__ ushort f32_to_bf16(float v) {
    uint u = __float_as_uint(v);
    u = (u + 0x7FFFu + ((u >> 16) & 1u)) >> 16;   // RNE
    return (ushort)u;
}

// ---------------------------------------------------------------------------
// kP: prep. Blocks 0..127: x fp32 NCHW -> xbf bf16 [N][128].
//            Blocks 128..143: emb fp32 -> bf16 + fp32 row norms.
//            Block 128 also zeroes the histogram.
// ---------------------------------------------------------------------------
__global__ __launch_bounds__(256) void kP_prep(
    const float* __restrict__ in, const float* __restrict__ emb,
    ushort* __restrict__ xbf, ushort* __restrict__ embbf,
    float* __restrict__ enorm, int* __restrict__ hist)
{
    const int blk = blockIdx.x, t = threadIdx.x;
    if (blk < 128) {
        const int n  = blk * 256 + t;
        const int b  = n >> 10, hw = n & 1023;
        const float* src = in + (size_t)b * (CC * HW) + hw;
        short8* dst = (short8*)(xbf + (size_t)n * 128);
#pragma unroll 2
        for (int c0 = 0; c0 < 16; ++c0) {
            union { short8 v; ushort u[8]; } p;
#pragma unroll
            for (int j = 0; j < 8; ++j)
                p.u[j] = f32_to_bf16(src[(size_t)(c0 * 8 + j) * HW]);
            dst[c0] = p.v;
        }
    } else {
        const int rr = t >> 2, q = t & 3;
        const int row = (blk - 128) * 64 + rr;
        const float4* src = (const float4*)(emb + (size_t)row * 128 + q * 32);
        short8* dst = (short8*)(embbf + (size_t)row * 128 + q * 32);
        float nrm = 0.f;
#pragma unroll
        for (int u2 = 0; u2 < 4; ++u2) {
            float4 a = src[u2 * 2], b = src[u2 * 2 + 1];
            float f[8] = {a.x, a.y, a.z, a.w, b.x, b.y, b.z, b.w};
            union { short8 v; ushort u[8]; } p;
#pragma unroll
            for (int j = 0; j < 8; ++j) {
                nrm = fmaf(f[j], f[j], nrm);
                p.u[j] = f32_to_bf16(f[j]);
            }
            dst[u2] = p.v;
        }
        nrm += __shfl_xor(nrm, 1);
        nrm += __shfl_xor(nrm, 2);
        if (q == 0) enorm[row] = nrm;
        if (blk == 128)
            for (int i = t; i < 1024; i += 256) hist[i] = 0;
    }
}

// ---------------------------------------------------------------------------
// kA2: bf16-MFMA candidate pass.
// ---------------------------------------------------------------------------
__global__ __launch_bounds__(128) void kA2_candidates(
    const ushort* __restrict__ xbf, const ushort* __restrict__ embbf,
    const float* __restrict__ enorm, int* __restrict__ cand8)
{
    __shared__ uint4 et16[2048];      // 32KB emb tile, aliased as merge buffer
    __shared__ float enl[1024];       // 4KB emb norms
    uint* keybuf = (uint*)et16;

    const int t    = threadIdx.x;
    const int lane = t & 63, w = t >> 6;
    const int quad = lane >> 4, m = lane & 15;
    const int rowBase = blockIdx.x * 64;
    const int rw = rowBase + w * 32;

    for (int i = t; i < 1024; i += 128) enl[i] = enorm[i];

    short8 A[2][4];
#pragma unroll
    for (int s = 0; s < 2; ++s)
#pragma unroll
    for (int kk = 0; kk < 4; ++kk)
        A[s][kk] = *(const short8*)(xbf + (size_t)(rw + s * 16 + m) * 128 + kk * 32 + quad * 8);

    uint kq[2][4][3];
#pragma unroll
    for (int s = 0; s < 2; ++s)
#pragma unroll
    for (int i = 0; i < 4; ++i)
        kq[s][i][0] = kq[s][i][1] = kq[s][i][2] = 0xFFFFFFFFu;

    const uint4* eg = (const uint4*)embbf;

    for (int tile = 0; tile < 8; ++tile) {
        __syncthreads();
#pragma unroll
        for (int u = 0; u < 16; ++u) {
            int c = u * 128 + t;
            int row = c >> 4, kb = c & 15;
            et16[row * 16 + (kb ^ (row & 7))] = eg[(size_t)(tile * 128 + row) * 16 + kb];
        }
        __syncthreads();
#pragma unroll
        for (int sub = 0; sub < 8; ++sub) {
            f32x4 acc0 = {0.f, 0.f, 0.f, 0.f}, acc1 = {0.f, 0.f, 0.f, 0.f};
#pragma unroll
            for (int kk = 0; kk < 4; ++kk) {
                short8 B = *(const short8*)&et16[(sub * 16 + m) * 16 + ((kk * 4 + quad) ^ (m & 7))];
                acc0 = __builtin_amdgcn_mfma_f32_16x16x32_bf16(A[0][kk], B, acc0, 0, 0, 0);
                acc1 = __builtin_amdgcn_mfma_f32_16x16x32_bf16(A[1][kk], B, acc1, 0, 0, 0);
            }
            const int col = tile * 128 + sub * 16 + m;
            const float en = enl[col];
#pragma unroll
            for (int i = 0; i < 4; ++i) {
                {
                    float sc = fmaf(-2.f, acc0[i], en);
                    uint u = __float_as_uint(sc);
                    u ^= (uint)(((int)u) >> 31) | 0x80000000u;   // sortable
                    uint key = (u & 0xFFFFFC00u) | (uint)col;
                    uint t0 = max(kq[0][i][0], key); kq[0][i][0] = min(kq[0][i][0], key);
                    uint t1 = max(kq[0][i][1], t0);  kq[0][i][1] = min(kq[0][i][1], t0);
                    kq[0][i][2] = min(kq[0][i][2], t1);
                }
                {
                    float sc = fmaf(-2.f, acc1[i], en);
                    uint u = __float_as_uint(sc);
                    u ^= (uint)(((int)u) >> 31) | 0x80000000u;
                    uint key = (u & 0xFFFFFC00u) | (uint)col;
                    uint t0 = max(kq[1][i][0], key); kq[1][i][0] = min(kq[1][i][0], key);
                    uint t1 = max(kq[1][i][1], t0);  kq[1][i][1] = min(kq[1][i][1], t0);
                    kq[1][i][2] = min(kq[1][i][2], t1);
                }
            }
        }
    }

    __syncthreads();
#pragma unroll
    for (int s = 0; s < 2; ++s)
#pragma unroll
    for (int i = 0; i < 4; ++i) {
        int rowl = w * 32 + s * 16 + quad * 4 + i;
#pragma unroll
        for (int j = 0; j < 3; ++j)
            keybuf[(m * 3 + j) * 65 + rowl] = kq[s][i][j];
    }
    __syncthreads();

    if (t < 64) {
        uint D[8];
#pragma unroll
        for (int s = 0; s < 8; ++s) D[s] = 0xFFFFFFFFu;
        for (int s = 0; s < 48; ++s) {
            uint k = keybuf[s * 65 + t];
            if (k < D[7]) {
                D[7] = k;
#pragma unroll
                for (int u = 7; u > 0; --u)
                    if (D[u] < D[u - 1]) { uint tmp = D[u]; D[u] = D[u - 1]; D[u - 1] = tmp; }
            }
        }
        int n = rowBase + t;
#pragma unroll
        for (int s = 0; s < 8; ++s) cand8[n * 8 + s] = (int)(D[s] & 1023u);
    }
}

// ---------------------------------------------------------------------------
// kB2: fp64 exact refine of 8 candidates -> true top-3 (tie-break by lower
// index). Also: 3rd-idx histogram + per-block fp64 loss partial (top-1 dist
// is exactly the e_latent_loss numerator).
// ---------------------------------------------------------------------------
__global__ __launch_bounds__(256) void kB2_refine(
    const float* __restrict__ in, const float* __restrict__ emb,
    const int* __restrict__ cand8, int* __restrict__ top3,
    int* __restrict__ hist, double* __restrict__ partials)
{
    __shared__ float x_lds[8192];   // [128][64]
    __shared__ double lsum[64];
    const int t = threadIdx.x;
    const int rowBase = blockIdx.x * 64;
    const int b = rowBase >> 10, hw0 = rowBase & 1023;
    const float* inB = in + (size_t)b * (CC * HW) + hw0;
    for (int i = t; i < 8192; i += 256) {
        int c = i >> 6, r = i & 63;
        x_lds[c * 64 + r] = inB[c * HW + r];
    }
    __syncthreads();

    const int r = t >> 2;     // row 0..63
    const int q = t & 3;      // c-chunk of 32
    const int n = rowBase + r;

    double dist[8]; int es[8];
    for (int s = 0; s < 8; ++s) {
        int e = cand8[n * 8 + s];
        es[s] = e;
        const float4* er = (const float4*)(emb + (size_t)e * DD + q * 32);
        double acc = 0.0;
#pragma unroll
        for (int u = 0; u < 8; ++u) {
            float4 ev = er[u];
            int c0 = q * 32 + u * 4;
            double a0 = (double)x_lds[(c0 + 0) * 64 + r] - (double)ev.x;
            double a1 = (double)x_lds[(c0 + 1) * 64 + r] - (double)ev.y;
            double a2 = (double)x_lds[(c0 + 2) * 64 + r] - (double)ev.z;
            double a3 = (double)x_lds[(c0 + 3) * 64 + r] - (double)ev.w;
            acc += a0 * a0 + a1 * a1 + a2 * a2 + a3 * a3;
        }
        acc += __shfl_xor(acc, 1);
        acc += __shfl_xor(acc, 2);
        dist[s] = acc;
    }

    if (q == 0) {
        bool used[8] = {false, false, false, false, false, false, false, false};
        int out_idx[3];
        double d_top1 = 0.0;
#pragma unroll
        for (int p = 0; p < 3; ++p) {
            double bd = 1.0e300; int bi = 0x7fffffff, bs = 0;
            for (int s = 0; s < 8; ++s) {
                if (used[s]) continue;
                if (dist[s] < bd || (dist[s] == bd && es[s] < bi)) {
                    bd = dist[s]; bi = es[s]; bs = s;
                }
            }
            used[bs] = true; out_idx[p] = bi;
            if (p == 0) d_top1 = bd;
        }
        top3[n * 4 + 0] = out_idx[0];
        top3[n * 4 + 1] = out_idx[1];
        top3[n * 4 + 2] = out_idx[2];
        atomicAdd(&hist[out_idx[2]], 1);
        lsum[r] = d_top1;
    }
    __syncthreads();
    if (t < 8) {
        double a = 0.0;
#pragma unroll
        for (int i = 0; i < 8; ++i) a += lsum[t * 8 + i];
        lsum[t] = a;
    }
    __syncthreads();
    if (t == 0) {
        double a = 0.0;
#pragma unroll
        for (int i = 0; i < 8; ++i) a += lsum[i];
        partials[blockIdx.x] = a;
    }
}

// ---------------------------------------------------------------------------
// kEpi: fused epilogue — one pass over all 201 MB of big outputs.
//   blocks 0..1023    : quantized_nchw (scalar stores; region is 4B-aligned)
//   blocks 1024..4095 : top_k_quantized (f32x2; region 8B-aligned)
//   blocks 4096..8191 : encodings zeros + inline one-hot (f32x2)
// Plain stores: L2 write-back coalesces full lines (nontemporal stores
// inflated HBM writes 3.5x and capped BW at 1.7 TB/s — round 4 evidence).
// ---------------------------------------------------------------------------
__global__ __launch_bounds__(256) void kEpi(
    const float* __restrict__ emb, const int* __restrict__ top3,
    float* __restrict__ out)
{
    const int blk = blockIdx.x, t = threadIdx.x;
    if (blk < 1024) {
        // quantized: 4.19M floats, 16 per thread
        float* dst = out + OFF_QUANT;
#pragma unroll 4
        for (int u = 0; u < 16; ++u) {
            int j  = blk * 4096 + u * 256 + t;
            int hw = j & 1023;
            int c  = (j >> 10) & 127;
            int bb = j >> 17;
            int n  = bb * 1024 + hw;
            int e  = top3[n * 4];
            dst[j] = emb[e * DD + c];
        }
    } else if (blk < 4096) {
        // top_k_quantized: 6.29M f32x2, 8 per thread
        const f32x2* e2 = (const f32x2*)emb;
        f32x2* dst = (f32x2*)(out + OFF_TOPK);
#pragma unroll 4
        for (int u = 0; u < 8; ++u) {
            int j  = (blk - 1024) * 2048 + u * 256 + t;
            int c2 = j & 63;
            int n  = (j >> 6) & 32767;
            int k  = j >> 21;
            int e  = top3[n * 4 + k];
            dst[j] = e2[e * 64 + c2];
        }
    } else {
        // encodings: 8 rows/block, 512 f32x2/row, one-hot of top3[.+2]
        const int row0 = (blk - 4096) * 8;
        const int r8 = t >> 5, seg = t & 31;
        const int row = row0 + r8;
        const int e = top3[row * 4 + 2];
        f32x2* dst = (f32x2*)(out + OFF_ENC) + (size_t)row * 512 + seg * 16;
#pragma unroll
        for (int u = 0; u < 16; ++u) {
            f32x2 v = {0.f, 0.f};
            if (seg == (e >> 5) && u == ((e >> 1) & 15))
                v[e & 1] = 1.0f;
            dst[u] = v;
        }
    }
}

// ---------------------------------------------------------------------------
// kF: finalize loss (512 partials) + perplexity (fp64 reductions).
// ---------------------------------------------------------------------------
__global__ __launch_bounds__(1024) void kF_final(
    const double* __restrict__ partials, const int* __restrict__ hist,
    float* __restrict__ out)
{
    __shared__ double sred[1024];
    const int t = threadIdx.x;
    sred[t] = (t < 512) ? partials[t] : 0.0;
    __syncthreads();
    for (int s = 512; s > 0; s >>= 1) {
        if (t < s) sred[t] += sred[t + s];
        __syncthreads();
    }
    if (t == 0) out[0] = (float)(0.25 * sred[0] / 4194304.0);
    __syncthreads();
    double p = (double)hist[t] / 32768.0;
    sred[t] = p * log(p + 1e-10);
    __syncthreads();
    for (int s = 512; s > 0; s >>= 1) {
        if (t < s) sred[t] += sred[t + s];
        __syncthreads();
    }
    if (t == 0) out[OFF_PERP] = (float)exp(-sred[0]);
}

extern "C" void kernel_launch(void* const* d_in, const int* in_sizes, int n_in,
                              void* d_out, int out_size, void* d_ws, size_t ws_size,
                              hipStream_t stream)
{
    const float* in  = (const float*)d_in[0];
    const float* emb = (const float*)d_in[1];
    float* out = (float*)d_out;
    char*  ws  = (char*)d_ws;

    double* partials = (double*)(ws + WS_PARTIALS);
    int*    hist     = (int*)(ws + WS_HIST);
    int*    cand8    = (int*)(ws + WS_CAND8);
    int*    top3     = (int*)(ws + WS_TOP3);
    ushort* embbf    = (ushort*)(ws + WS_EMBBF);
    float*  enorm    = (float*)(ws + WS_ENORM);
    // xbf scratch lives in the top_k output region (16B-aligned at +2 floats);
    // kEpi's topk writes fully overwrite it afterwards.
    ushort* xbf = (ushort*)(out + OFF_TOPK + 2);

    kP_prep       <<<dim3(144), dim3(256), 0, stream>>>(in, emb, xbf, embbf, enorm, hist);
    kA2_candidates<<<dim3(512), dim3(128), 0, stream>>>(xbf, embbf, enorm, cand8);
    kB2_refine    <<<dim3(512), dim3(256), 0, stream>>>(in, emb, cand8, top3, hist, partials);
    kEpi          <<<dim3(8192), dim3(256), 0, stream>>>(emb, top3, out);
    kF_final      <<<dim3(1), dim3(1024), 0, stream>>>(partials, hist, out);
}

// Round 6
// 328.599 us; speedup vs baseline: 2.1435x; 1.0868x over previous
//
#include <hip/hip_runtime.h>

// Problem constants
#define BB 32
#define CC 128
#define HW 1024            // 32*32
#define NN 32768           // BB*HW
#define KK 1024            // num embeddings
#define DD 128             // embedding dim
// Output offsets (floats): (loss, quantized_nchw, perplexity, encodings, top_k_quantized)
#define OFF_QUANT 1
#define OFF_PERP  4194305
#define OFF_ENC   4194306
#define OFF_TOPK  37748738

// ws layout (bytes)
#define WS_PARTIALS 0          // 512 doubles used
#define WS_HIST     32768      // 1024 ints
#define WS_CAND8    36864      // 32768*8 ints = 1 MiB
#define WS_TOP3     1085440    // 32768*4 ints = 512 KiB
#define WS_EMBBF    1609728    // 1024*128 ushort = 256 KiB
#define WS_ENORM    1871872    // 1024 float = 4 KiB

typedef __attribute__((ext_vector_type(8))) short short8;
typedef __attribute__((ext_vector_type(4))) float f32x4;
typedef __attribute__((ext_vector_type(2))) float f32x2;

__device__ __forceinline__ ushort f32_to_bf16(float v) {
    uint u = __float_as_uint(v);
    u = (u + 0x7FFFu + ((u >> 16) & 1u)) >> 16;   // RNE
    return (ushort)u;
}

// ---------------------------------------------------------------------------
// kP: prep. Blocks 0..127: x fp32 NCHW -> xbf bf16 [N][128].
//            Blocks 128..143: emb fp32 -> bf16 + fp32 row norms.
//            Block 128 also zeroes the histogram.
// ---------------------------------------------------------------------------
__global__ __launch_bounds__(256) void kP_prep(
    const float* __restrict__ in, const float* __restrict__ emb,
    ushort* __restrict__ xbf, ushort* __restrict__ embbf,
    float* __restrict__ enorm, int* __restrict__ hist)
{
    const int blk = blockIdx.x, t = threadIdx.x;
    if (blk < 128) {
        const int n  = blk * 256 + t;
        const int b  = n >> 10, hw = n & 1023;
        const float* src = in + (size_t)b * (CC * HW) + hw;
        short8* dst = (short8*)(xbf + (size_t)n * 128);
#pragma unroll 2
        for (int c0 = 0; c0 < 16; ++c0) {
            union { short8 v; ushort u[8]; } p;
#pragma unroll
            for (int j = 0; j < 8; ++j)
                p.u[j] = f32_to_bf16(src[(size_t)(c0 * 8 + j) * HW]);
            dst[c0] = p.v;
        }
    } else {
        const int rr = t >> 2, q = t & 3;
        const int row = (blk - 128) * 64 + rr;
        const float4* src = (const float4*)(emb + (size_t)row * 128 + q * 32);
        short8* dst = (short8*)(embbf + (size_t)row * 128 + q * 32);
        float nrm = 0.f;
#pragma unroll
        for (int u2 = 0; u2 < 4; ++u2) {
            float4 a = src[u2 * 2], b = src[u2 * 2 + 1];
            float f[8] = {a.x, a.y, a.z, a.w, b.x, b.y, b.z, b.w};
            union { short8 v; ushort u[8]; } p;
#pragma unroll
            for (int j = 0; j < 8; ++j) {
                nrm = fmaf(f[j], f[j], nrm);
                p.u[j] = f32_to_bf16(f[j]);
            }
            dst[u2] = p.v;
        }
        nrm += __shfl_xor(nrm, 1);
        nrm += __shfl_xor(nrm, 2);
        if (q == 0) enorm[row] = nrm;
        if (blk == 128)
            for (int i = t; i < 1024; i += 256) hist[i] = 0;
    }
}

// ---------------------------------------------------------------------------
// kA2: bf16-MFMA candidate pass.
// ---------------------------------------------------------------------------
__global__ __launch_bounds__(128) void kA2_candidates(
    const ushort* __restrict__ xbf, const ushort* __restrict__ embbf,
    const float* __restrict__ enorm, int* __restrict__ cand8)
{
    __shared__ uint4 et16[2048];      // 32KB emb tile, aliased as merge buffer
    __shared__ float enl[1024];       // 4KB emb norms
    uint* keybuf = (uint*)et16;

    const int t    = threadIdx.x;
    const int lane = t & 63, w = t >> 6;
    const int quad = lane >> 4, m = lane & 15;
    const int rowBase = blockIdx.x * 64;
    const int rw = rowBase + w * 32;

    for (int i = t; i < 1024; i += 128) enl[i] = enorm[i];

    short8 A[2][4];
#pragma unroll
    for (int s = 0; s < 2; ++s)
#pragma unroll
    for (int kk = 0; kk < 4; ++kk)
        A[s][kk] = *(const short8*)(xbf + (size_t)(rw + s * 16 + m) * 128 + kk * 32 + quad * 8);

    uint kq[2][4][3];
#pragma unroll
    for (int s = 0; s < 2; ++s)
#pragma unroll
    for (int i = 0; i < 4; ++i)
        kq[s][i][0] = kq[s][i][1] = kq[s][i][2] = 0xFFFFFFFFu;

    const uint4* eg = (const uint4*)embbf;

    for (int tile = 0; tile < 8; ++tile) {
        __syncthreads();
#pragma unroll
        for (int u = 0; u < 16; ++u) {
            int c = u * 128 + t;
            int row = c >> 4, kb = c & 15;
            et16[row * 16 + (kb ^ (row & 7))] = eg[(size_t)(tile * 128 + row) * 16 + kb];
        }
        __syncthreads();
#pragma unroll
        for (int sub = 0; sub < 8; ++sub) {
            f32x4 acc0 = {0.f, 0.f, 0.f, 0.f}, acc1 = {0.f, 0.f, 0.f, 0.f};
#pragma unroll
            for (int kk = 0; kk < 4; ++kk) {
                short8 B = *(const short8*)&et16[(sub * 16 + m) * 16 + ((kk * 4 + quad) ^ (m & 7))];
                acc0 = __builtin_amdgcn_mfma_f32_16x16x32_bf16(A[0][kk], B, acc0, 0, 0, 0);
                acc1 = __builtin_amdgcn_mfma_f32_16x16x32_bf16(A[1][kk], B, acc1, 0, 0, 0);
            }
            const int col = tile * 128 + sub * 16 + m;
            const float en = enl[col];
#pragma unroll
            for (int i = 0; i < 4; ++i) {
                {
                    float sc = fmaf(-2.f, acc0[i], en);
                    uint u = __float_as_uint(sc);
                    u ^= (uint)(((int)u) >> 31) | 0x80000000u;   // sortable
                    uint key = (u & 0xFFFFFC00u) | (uint)col;
                    uint t0 = max(kq[0][i][0], key); kq[0][i][0] = min(kq[0][i][0], key);
                    uint t1 = max(kq[0][i][1], t0);  kq[0][i][1] = min(kq[0][i][1], t0);
                    kq[0][i][2] = min(kq[0][i][2], t1);
                }
                {
                    float sc = fmaf(-2.f, acc1[i], en);
                    uint u = __float_as_uint(sc);
                    u ^= (uint)(((int)u) >> 31) | 0x80000000u;
                    uint key = (u & 0xFFFFFC00u) | (uint)col;
                    uint t0 = max(kq[1][i][0], key); kq[1][i][0] = min(kq[1][i][0], key);
                    uint t1 = max(kq[1][i][1], t0);  kq[1][i][1] = min(kq[1][i][1], t0);
                    kq[1][i][2] = min(kq[1][i][2], t1);
                }
            }
        }
    }

    __syncthreads();
#pragma unroll
    for (int s = 0; s < 2; ++s)
#pragma unroll
    for (int i = 0; i < 4; ++i) {
        int rowl = w * 32 + s * 16 + quad * 4 + i;
#pragma unroll
        for (int j = 0; j < 3; ++j)
            keybuf[(m * 3 + j) * 65 + rowl] = kq[s][i][j];
    }
    __syncthreads();

    if (t < 64) {
        uint D[8];
#pragma unroll
        for (int s = 0; s < 8; ++s) D[s] = 0xFFFFFFFFu;
        for (int s = 0; s < 48; ++s) {
            uint k = keybuf[s * 65 + t];
            if (k < D[7]) {
                D[7] = k;
#pragma unroll
                for (int u = 7; u > 0; --u)
                    if (D[u] < D[u - 1]) { uint tmp = D[u]; D[u] = D[u - 1]; D[u - 1] = tmp; }
            }
        }
        int n = rowBase + t;
#pragma unroll
        for (int s = 0; s < 8; ++s) cand8[n * 8 + s] = (int)(D[s] & 1023u);
    }
}

// ---------------------------------------------------------------------------
// kB2: fp64 exact refine of 8 candidates -> true top-3 (tie-break by lower
// index). Also: 3rd-idx histogram + per-block fp64 loss partial (top-1 dist
// is exactly the e_latent_loss numerator).
// ---------------------------------------------------------------------------
__global__ __launch_bounds__(256) void kB2_refine(
    const float* __restrict__ in, const float* __restrict__ emb,
    const int* __restrict__ cand8, int* __restrict__ top3,
    int* __restrict__ hist, double* __restrict__ partials)
{
    __shared__ float x_lds[8192];   // [128][64]
    __shared__ double lsum[64];
    const int t = threadIdx.x;
    const int rowBase = blockIdx.x * 64;
    const int b = rowBase >> 10, hw0 = rowBase & 1023;
    const float* inB = in + (size_t)b * (CC * HW) + hw0;
    for (int i = t; i < 8192; i += 256) {
        int c = i >> 6, r = i & 63;
        x_lds[c * 64 + r] = inB[c * HW + r];
    }
    __syncthreads();

    const int r = t >> 2;     // row 0..63
    const int q = t & 3;      // c-chunk of 32
    const int n = rowBase + r;

    double dist[8]; int es[8];
    for (int s = 0; s < 8; ++s) {
        int e = cand8[n * 8 + s];
        es[s] = e;
        const float4* er = (const float4*)(emb + (size_t)e * DD + q * 32);
        double acc = 0.0;
#pragma unroll
        for (int u = 0; u < 8; ++u) {
            float4 ev = er[u];
            int c0 = q * 32 + u * 4;
            double a0 = (double)x_lds[(c0 + 0) * 64 + r] - (double)ev.x;
            double a1 = (double)x_lds[(c0 + 1) * 64 + r] - (double)ev.y;
            double a2 = (double)x_lds[(c0 + 2) * 64 + r] - (double)ev.z;
            double a3 = (double)x_lds[(c0 + 3) * 64 + r] - (double)ev.w;
            acc += a0 * a0 + a1 * a1 + a2 * a2 + a3 * a3;
        }
        acc += __shfl_xor(acc, 1);
        acc += __shfl_xor(acc, 2);
        dist[s] = acc;
    }

    if (q == 0) {
        bool used[8] = {false, false, false, false, false, false, false, false};
        int out_idx[3];
        double d_top1 = 0.0;
#pragma unroll
        for (int p = 0; p < 3; ++p) {
            double bd = 1.0e300; int bi = 0x7fffffff, bs = 0;
            for (int s = 0; s < 8; ++s) {
                if (used[s]) continue;
                if (dist[s] < bd || (dist[s] == bd && es[s] < bi)) {
                    bd = dist[s]; bi = es[s]; bs = s;
                }
            }
            used[bs] = true; out_idx[p] = bi;
            if (p == 0) d_top1 = bd;
        }
        top3[n * 4 + 0] = out_idx[0];
        top3[n * 4 + 1] = out_idx[1];
        top3[n * 4 + 2] = out_idx[2];
        atomicAdd(&hist[out_idx[2]], 1);
        lsum[r] = d_top1;
    }
    __syncthreads();
    if (t < 8) {
        double a = 0.0;
#pragma unroll
        for (int i = 0; i < 8; ++i) a += lsum[t * 8 + i];
        lsum[t] = a;
    }
    __syncthreads();
    if (t == 0) {
        double a = 0.0;
#pragma unroll
        for (int i = 0; i < 8; ++i) a += lsum[i];
        partials[blockIdx.x] = a;
    }
}

// ---------------------------------------------------------------------------
// kEpi: fused epilogue — one pass over all 201 MB of big outputs.
//   blocks 0..1023    : quantized_nchw (coalesced scalar stores, hoisted idx)
//   blocks 1024..4095 : top_k_quantized (f32x2, contiguous per instruction)
//   blocks 4096..8191 : encodings one-hot (f32x2, contiguous 2KB/wave-instr)
//   block 8192        : finalize loss + perplexity (fp64)
// Plain stores: L2 write-back coalesces lines (nontemporal inflated HBM
// writes 3.5x and capped BW at 1.7 TB/s — round 4 evidence).
// ---------------------------------------------------------------------------
__global__ __launch_bounds__(256) void kEpi(
    const float* __restrict__ emb, const int* __restrict__ top3,
    const double* __restrict__ partials, const int* __restrict__ hist,
    float* __restrict__ out)
{
    const int blk = blockIdx.x, t = threadIdx.x;
    if (blk < 1024) {
        // quantized: block covers j in [blk*4096, blk*4096+4096) of NCHW.
        // bb fixed per block; 4 distinct rows (hw groups) per thread.
        float* dst = out + OFF_QUANT;
        const int bb = blk >> 5;
        int e4[4];
#pragma unroll
        for (int v = 0; v < 4; ++v)
            e4[v] = top3[(bb * 1024 + v * 256 + t) * 4];
#pragma unroll 4
        for (int u = 0; u < 16; ++u) {
            int j = blk * 4096 + u * 256 + t;
            int c = (4 * blk + (u >> 2)) & 127;
            dst[j] = emb[e4[u & 3] * DD + c];
        }
    } else if (blk < 4096) {
        // top_k_quantized: 6.29M f32x2, contiguous 256-f32x2 runs per instr
        const f32x2* e2 = (const f32x2*)emb;
        f32x2* dst = (f32x2*)(out + OFF_TOPK);
#pragma unroll 4
        for (int u = 0; u < 8; ++u) {
            int j  = (blk - 1024) * 2048 + u * 256 + t;
            int c2 = j & 63;
            int n  = (j >> 6) & 32767;
            int k  = j >> 21;
            int e  = top3[n * 4 + k];
            dst[j] = e2[e * 64 + c2];
        }
    } else if (blk < 8192) {
        // encodings: 8 rows/block, 4096 f32x2; lane t writes idx u*256+t
        // -> each instruction is a contiguous 2KB wave-run.
        const int row0 = (blk - 4096) * 8;
        __shared__ int e8[8];
        if (t < 8) e8[t] = top3[(row0 + t) * 4 + 2];
        __syncthreads();
        f32x2* dst = (f32x2*)(out + OFF_ENC) + (size_t)row0 * 512;
#pragma unroll 4
        for (int u = 0; u < 16; ++u) {
            int idx = u * 256 + t;
            int e = e8[idx >> 9];
            int col = idx & 511;
            f32x2 v = {0.f, 0.f};
            if ((e >> 1) == col) v[e & 1] = 1.0f;
            dst[idx] = v;
        }
    } else {
        // finals: loss from 512 partials, perplexity from 1024-bin hist
        __shared__ double sred[256];
        sred[t] = partials[t] + partials[t + 256];
        __syncthreads();
        for (int s = 128; s > 0; s >>= 1) {
            if (t < s) sred[t] += sred[t + s];
            __syncthreads();
        }
        if (t == 0) out[0] = (float)(0.25 * sred[0] / 4194304.0);
        __syncthreads();
        double s2 = 0.0;
#pragma unroll
        for (int i = 0; i < 4; ++i) {
            double p = (double)hist[t + i * 256] * (1.0 / 32768.0);
            s2 += p * log(p + 1e-10);
        }
        sred[t] = s2;
        __syncthreads();
        for (int s = 128; s > 0; s >>= 1) {
            if (t < s) sred[t] += sred[t + s];
            __syncthreads();
        }
        if (t == 0) out[OFF_PERP] = (float)exp(-sred[0]);
    }
}

extern "C" void kernel_launch(void* const* d_in, const int* in_sizes, int n_in,
                              void* d_out, int out_size, void* d_ws, size_t ws_size,
                              hipStream_t stream)
{
    const float* in  = (const float*)d_in[0];
    const float* emb = (const float*)d_in[1];
    float* out = (float*)d_out;
    char*  ws  = (char*)d_ws;

    double* partials = (double*)(ws + WS_PARTIALS);
    int*    hist     = (int*)(ws + WS_HIST);
    int*    cand8    = (int*)(ws + WS_CAND8);
    int*    top3     = (int*)(ws + WS_TOP3);
    ushort* embbf    = (ushort*)(ws + WS_EMBBF);
    float*  enorm    = (float*)(ws + WS_ENORM);
    // xbf scratch lives in the top_k output region (16B-aligned at +2 floats);
    // kEpi's topk writes fully overwrite it afterwards.
    ushort* xbf = (ushort*)(out + OFF_TOPK + 2);

    kP_prep       <<<dim3(144), dim3(256), 0, stream>>>(in, emb, xbf, embbf, enorm, hist);
    kA2_candidates<<<dim3(512), dim3(128), 0, stream>>>(xbf, embbf, enorm, cand8);
    kB2_refine    <<<dim3(512), dim3(256), 0, stream>>>(in, emb, cand8, top3, hist, partials);
    kEpi          <<<dim3(8193), dim3(256), 0, stream>>>(emb, top3, partials, hist, out);
}